// Round 8
// baseline (206.739 us; speedup 1.0000x reference)
//
#include <hip/hip_runtime.h>

// CascadeHierarchicalEmbedding, R8 (= R7 with NT-store type fix).
// - emb0/emb1: per-wave 4 KB LDS buffers, global_load_lds w/ XOR-swizzled
//   global source, prefetched one tile ahead (counted vmcnt, never drained).
// - emb2: REGISTER-prefetched one tile ahead (L2-resident table; latency
//   covered by a full iteration), not LDS.
// - W1 fragments in LDS (16 KB/block, shared by 8 waves), JIT pair reads.
// - output via nontemporal stores (never re-read) to cut L2 pollution that
//   evicted emb2 in R6.  NT stores use clang ext_vector f32x4 (HIP float4
//   is a struct and is rejected by __builtin_nontemporal_store).
// - 8 waves x 512 thr, 80 KB LDS -> 2 blocks/CU = 16 waves/CU resident.
// - per-iter VMEM order: G8(t+nw) E4(t+nw) I9(t+2nw) S4(t); top vmcnt(13).

#define WPB 8       // waves per block (512 threads)
#define NBLK 256    // 256 blocks x 8 waves = 2048 waves = exactly resident

typedef float f32x4 __attribute__((ext_vector_type(4)));
typedef short v8s __attribute__((ext_vector_type(8)));
typedef __attribute__((address_space(3))) uint32_t lds_u32_t;
typedef __attribute__((address_space(1))) const uint32_t glb_u32_t;

static __device__ __forceinline__ unsigned short bf16_rne(float f) {
  union { float f; unsigned int u; } a; a.f = f;
  return (unsigned short)((a.u + 0x7FFFu + ((a.u >> 16) & 1u)) >> 16);
}

// Pack W1 (f32 [128][32]) into bf16 A-fragments (W1^T). gate0: frags 0..7,
// gate1: frags 8..15. fragid = gate*8 + kt*2 + nt; elem (lane,j):
// k = kt*32 + (lane>>4)*8 + j, o = nt*16 + (lane&15) -> w1[k][o].
__global__ __launch_bounds__(256) void prep_frags(
    const float* __restrict__ g0w1, const float* __restrict__ g1w1,
    unsigned short* __restrict__ wsf) {
  int t = blockIdx.x * 256 + threadIdx.x;
  if (t >= 1024) return;
  int lane = t & 63, fragid = t >> 6;
  int gate = fragid >> 3, kt = (fragid >> 1) & 3, nt = fragid & 1;
  const float* __restrict__ w1 = gate ? g1w1 : g0w1;
#pragma unroll
  for (int j = 0; j < 8; ++j) {
    int k = kt * 32 + ((lane >> 4) << 3) + j;
    int o = nt * 16 + (lane & 15);
    wsf[fragid * 512 + lane * 8 + j] = bf16_rne(w1[k * 32 + o]);
  }
}

// One gate level: z = W1^T x (bf16-hi), W frags JIT-read from LDS in pairs;
// relu+layer2 per lane, 2-shuffle reduce, sigmoid, blend cur in place.
static __device__ __forceinline__ void gate_apply(
    const float (&fine)[16], float (&cur)[16], const uint4* wfl, int lane,
    f32x4 b1a, f32x4 b1b, f32x4 w2a, f32x4 w2b, float b2s) {
  v8s xf0, xf1, xc0, xc1;
#pragma unroll
  for (int e = 0; e < 8; ++e) {
    xf0[e] = (short)bf16_rne(fine[e]);
    xf1[e] = (short)bf16_rne(fine[8 + e]);
    xc0[e] = (short)bf16_rne(cur[e]);
    xc1[e] = (short)bf16_rne(cur[8 + e]);
  }
  f32x4 acc0 = b1a, acc1 = b1b;
  {
    uint4 wa = wfl[0 * 64 + lane], wb = wfl[1 * 64 + lane];
    acc0 = __builtin_amdgcn_mfma_f32_16x16x32_bf16(*(const v8s*)&wa, xf0, acc0, 0, 0, 0);
    acc1 = __builtin_amdgcn_mfma_f32_16x16x32_bf16(*(const v8s*)&wb, xf0, acc1, 0, 0, 0);
  }
  {
    uint4 wa = wfl[2 * 64 + lane], wb = wfl[3 * 64 + lane];
    acc0 = __builtin_amdgcn_mfma_f32_16x16x32_bf16(*(const v8s*)&wa, xf1, acc0, 0, 0, 0);
    acc1 = __builtin_amdgcn_mfma_f32_16x16x32_bf16(*(const v8s*)&wb, xf1, acc1, 0, 0, 0);
  }
  {
    uint4 wa = wfl[4 * 64 + lane], wb = wfl[5 * 64 + lane];
    acc0 = __builtin_amdgcn_mfma_f32_16x16x32_bf16(*(const v8s*)&wa, xc0, acc0, 0, 0, 0);
    acc1 = __builtin_amdgcn_mfma_f32_16x16x32_bf16(*(const v8s*)&wb, xc0, acc1, 0, 0, 0);
  }
  {
    uint4 wa = wfl[6 * 64 + lane], wb = wfl[7 * 64 + lane];
    acc0 = __builtin_amdgcn_mfma_f32_16x16x32_bf16(*(const v8s*)&wa, xc1, acc0, 0, 0, 0);
    acc1 = __builtin_amdgcn_mfma_f32_16x16x32_bf16(*(const v8s*)&wb, xc1, acc1, 0, 0, 0);
  }
  float zp = 0.f;
#pragma unroll
  for (int j = 0; j < 4; ++j)
    zp += fmaxf(acc0[j], 0.f) * w2a[j] + fmaxf(acc1[j], 0.f) * w2b[j];
  zp += __shfl_xor(zp, 16);
  zp += __shfl_xor(zp, 32);
  float g = 1.f / (1.f + __expf(-(zp + b2s)));
#pragma unroll
  for (int e = 0; e < 16; ++e) cur[e] = fmaf(g, fine[e] - cur[e], cur[e]);
}

__global__ __launch_bounds__(512, 4) void cascade_pipe(
    const int* __restrict__ ids0, const int* __restrict__ ids1,
    const int* __restrict__ ids2,
    const float* __restrict__ emb0, const float* __restrict__ emb1,
    const float* __restrict__ emb2,
    const uint4* __restrict__ wfrag,
    const float* __restrict__ b1_0, const float* __restrict__ w2_0,
    const float* __restrict__ b2_0,
    const float* __restrict__ b1_1, const float* __restrict__ w2_1,
    const float* __restrict__ b2_1,
    float* __restrict__ out, int n) {
  __shared__ uint4 WF[1024];            // 16 KB: frag f at WF[f*64 + lane]
  __shared__ float4 EB[WPB][2][256];    // per wave: [0]=emb1, [1]=emb0
  const int tid = threadIdx.x, lane = tid & 63, wave = tid >> 6;
  const int q = lane >> 4, t16 = lane & 15;
  const int ntiles = n >> 4;
  const int nw = NBLK * WPB;
  int tile = blockIdx.x * WPB + wave;

  // stage W fragments into LDS (512 thr x 2 x 16 B = 16 KB, linear)
  __builtin_amdgcn_global_load_lds(
      (glb_u32_t*)((const char*)wfrag + tid * 16),
      (lds_u32_t*)(uint32_t*)&WF[tid], 16, 0, 0);
  __builtin_amdgcn_global_load_lds(
      (glb_u32_t*)((const char*)wfrag + 8192 + tid * 16),
      (lds_u32_t*)(uint32_t*)&WF[512 + tid], 16, 0, 0);

  // layer-2 params (per-lane, q-dependent)
  const f32x4 b1a0 = *(const f32x4*)&b1_0[q * 4], b1b0 = *(const f32x4*)&b1_0[16 + q * 4];
  const f32x4 w2a0 = *(const f32x4*)&w2_0[q * 4], w2b0 = *(const f32x4*)&w2_0[16 + q * 4];
  const f32x4 b1a1 = *(const f32x4*)&b1_1[q * 4], b1b1 = *(const f32x4*)&b1_1[16 + q * 4];
  const f32x4 w2a1 = *(const f32x4*)&w2_1[q * 4], w2b1 = *(const f32x4*)&w2_1[16 + q * 4];
  const float b2s0 = b2_0[0], b2s1 = b2_1[0];

  // G: 8 gathers (emb1+emb0) for a tile, XOR-swizzled via global source.
  auto issueA = [&](const int (&i1)[4], const int (&i0)[4]) {
#pragma unroll
    for (int s = 0; s < 4; ++s) {
      int swb = ((t16 ^ (s * 4 + q)) << 4);
      __builtin_amdgcn_global_load_lds(
          (glb_u32_t*)((const char*)emb1 + (((long)i1[s]) << 8) + swb),
          (lds_u32_t*)(uint32_t*)&EB[wave][0][s * 64], 16, 0, 0);
      __builtin_amdgcn_global_load_lds(
          (glb_u32_t*)((const char*)emb0 + (((long)i0[s]) << 8) + swb),
          (lds_u32_t*)(uint32_t*)&EB[wave][1][s * 64], 16, 0, 0);
    }
  };

  int jA1[4], jA0[4], jC2n;       // ids for the NEXT tile to issue (t+nw)
  float4 c0n, c1n, c2n, c3n;      // emb2 register prefetch (next tile)

  // E: 4 per-lane emb2 loads in compute layout for token t16 of the tile
  auto issueE = [&](int id2) {
    const char* rb = (const char*)emb2 + (((long)id2) << 8) + q * 32;
    c0n = *(const float4*)(rb);
    c1n = *(const float4*)(rb + 16);
    c2n = *(const float4*)(rb + 128);
    c3n = *(const float4*)(rb + 144);
  };

  // ---- prologue
  {
    int tp = (tile < ntiles) ? tile : 0;
    int tb = tp << 4;
    int a1[4], a0[4];
#pragma unroll
    for (int s = 0; s < 4; ++s) {
      a1[s] = ids1[tb + s * 4 + q];
      a0[s] = ids0[tb + s * 4 + q];
    }
    int c2 = ids2[tb + t16];
    int tn = tp + nw; if (tn >= ntiles) tn = 0;
    int tb2 = tn << 4;
#pragma unroll
    for (int s = 0; s < 4; ++s) {
      jA1[s] = ids1[tb2 + s * 4 + q];
      jA0[s] = ids0[tb2 + s * 4 + q];
    }
    jC2n = ids2[tb2 + t16];
    __syncthreads();            // WF staged (barrier drains counters)
    issueA(a1, a0);             // G(t0)
    issueE(c2);                 // E(t0) -> c0n..c3n
    asm volatile("s_waitcnt vmcnt(0)" ::: "memory");  // one-time drain
    __builtin_amdgcn_sched_barrier(0);
  }

  for (; tile < ntiles; tile += nw) {
    // outstanding (in-order) from prev iter: I9 + S4 = 13 -> G8+E4 retired
    asm volatile("s_waitcnt vmcnt(13)" ::: "memory");
    __builtin_amdgcn_sched_barrier(0);

    // cur from emb2 register prefetch
    float curv[16];
    *(float4*)&curv[0]  = c0n;
    *(float4*)&curv[4]  = c1n;
    *(float4*)&curv[8]  = c2n;
    *(float4*)&curv[12] = c3n;

    // fine1 from LDS (swizzled chunks of row t16)
    float f1v[16];
#pragma unroll
    for (int e = 0; e < 4; ++e) {
      int ci = (2 * q + (e & 1) + 8 * (e >> 1)) ^ t16;
      *(float4*)&f1v[e * 4] = EB[wave][0][t16 * 16 + ci];
    }
    // gate level 1 (fine = emb1); EB[wave][1] untouched
    gate_apply(f1v, curv, &WF[512], lane, b1a1, b1b1, w2a1, w2b1, b2s1);

    // fine0 from LDS, then free the buffers for the next tile's gathers
    float f0v[16];
#pragma unroll
    for (int e = 0; e < 4; ++e) {
      int ci = (2 * q + (e & 1) + 8 * (e >> 1)) ^ t16;
      *(float4*)&f0v[e * 4] = EB[wave][1][t16 * 16 + ci];
    }
    asm volatile("s_waitcnt lgkmcnt(0)" ::: "memory");  // reads done -> LDS free
    __builtin_amdgcn_sched_barrier(0);

    // G: gathers for tile+nw ; E: emb2 regs for tile+nw
    issueA(jA1, jA0);
    issueE(jC2n);
    __builtin_amdgcn_sched_barrier(0);

    // I: ids for tile+2nw (9 loads)
    {
      int tn2 = tile + 2 * nw; if (tn2 >= ntiles) tn2 = 0;
      int tb2 = tn2 << 4;
#pragma unroll
      for (int s = 0; s < 4; ++s) {
        jA1[s] = ids1[tb2 + s * 4 + q];
        jA0[s] = ids0[tb2 + s * 4 + q];
      }
      jC2n = ids2[tb2 + t16];
    }
    __builtin_amdgcn_sched_barrier(0);

    // gate level 0 (fine = emb0)
    gate_apply(f0v, curv, &WF[0], lane, b1a0, b1b0, w2a0, w2b0, b2s0);

    // S: nontemporal store of token (tile*16 + t16), 4 x 16 B
    long tok = ((long)tile << 4) + t16;
    if (tok < n) {
      f32x4* op = (f32x4*)out + (tok << 4);
      f32x4 o0 = {curv[0], curv[1], curv[2], curv[3]};
      f32x4 o1 = {curv[4], curv[5], curv[6], curv[7]};
      f32x4 o2 = {curv[8], curv[9], curv[10], curv[11]};
      f32x4 o3 = {curv[12], curv[13], curv[14], curv[15]};
      __builtin_nontemporal_store(o0, op + 2 * q + 0);
      __builtin_nontemporal_store(o1, op + 2 * q + 1);
      __builtin_nontemporal_store(o2, op + 8 + 2 * q + 0);
      __builtin_nontemporal_store(o3, op + 8 + 2 * q + 1);
    }
  }
}

extern "C" void kernel_launch(void* const* d_in, const int* in_sizes, int n_in,
                              void* d_out, int out_size, void* d_ws,
                              size_t ws_size, hipStream_t stream) {
  const int* ids0 = (const int*)d_in[0];
  const int* ids1 = (const int*)d_in[1];
  const int* ids2 = (const int*)d_in[2];
  const float* emb0 = (const float*)d_in[3];
  const float* emb1 = (const float*)d_in[4];
  const float* emb2 = (const float*)d_in[5];
  const float* g0w1 = (const float*)d_in[6];
  const float* g0b1 = (const float*)d_in[7];
  const float* g0w2 = (const float*)d_in[8];
  const float* g0b2 = (const float*)d_in[9];
  const float* g1w1 = (const float*)d_in[10];
  const float* g1b1 = (const float*)d_in[11];
  const float* g1w2 = (const float*)d_in[12];
  const float* g1b2 = (const float*)d_in[13];
  float* out = (float*)d_out;

  int n = in_sizes[0];  // B*H tokens

  hipLaunchKernelGGL(prep_frags, dim3(4), dim3(256), 0, stream,
                     g0w1, g1w1, (unsigned short*)d_ws);

  hipLaunchKernelGGL(cascade_pipe, dim3(NBLK), dim3(512), 0, stream,
                     ids0, ids1, ids2, emb0, emb1, emb2,
                     (const uint4*)d_ws,
                     g0b1, g0w2, g0b2,
                     g1b1, g1w2, g1b2,
                     out, n);
}

// Round 9
// 132.422 us; speedup vs baseline: 1.5612x; 1.5612x over previous
//
#include <hip/hip_runtime.h>

// CascadeHierarchicalEmbedding, R9: R5's proven memory structure (best: 139.5us,
// 489 MB) + more resident waves.
// - ALL THREE tables gathered via global_load_lds into per-wave 4 KB LDS
//   buffers, XOR-swizzled via pre-swizzled global source (R5 path: FETCH 273MB).
// - plain stores (L2 merges q-strided half-lines to exactly 204.8 MB; NT broke
//   this in R8).
// - W1 fragments in shared LDS (16 KB/block, JIT pair reads) -> VGPR ~115.
// - 4 waves/block, LDS 64 KB -> 2 blocks/CU = 8 waves/CU; grid 512 blocks =
//   2048 waves exactly resident; ntiles 51200 -> exactly 25 iters/wave.
// - counted vmcnt: top-of-loop vmcnt(16) (= ids12 + stores4) covers exactly
//   the 12 gathers; prologue vmcnt(12) makes iteration 0 safe.

#define WPB 4       // waves per block (256 threads)
#define NBLK 512    // 512 blocks x 4 waves = 2048 waves = 2 blocks/CU

typedef float f32x4 __attribute__((ext_vector_type(4)));
typedef short v8s __attribute__((ext_vector_type(8)));
typedef __attribute__((address_space(3))) uint32_t lds_u32_t;
typedef __attribute__((address_space(1))) const uint32_t glb_u32_t;

static __device__ __forceinline__ unsigned short bf16_rne(float f) {
  union { float f; unsigned int u; } a; a.f = f;
  return (unsigned short)((a.u + 0x7FFFu + ((a.u >> 16) & 1u)) >> 16);
}

// Pack W1 (f32 [128][32]) into bf16 A-fragments (W1^T). gate0: frags 0..7,
// gate1: frags 8..15. fragid = gate*8 + kt*2 + nt; elem (lane,j):
// k = kt*32 + (lane>>4)*8 + j, o = nt*16 + (lane&15) -> w1[k][o].
__global__ __launch_bounds__(256) void prep_frags(
    const float* __restrict__ g0w1, const float* __restrict__ g1w1,
    unsigned short* __restrict__ wsf) {
  int t = blockIdx.x * 256 + threadIdx.x;
  if (t >= 1024) return;
  int lane = t & 63, fragid = t >> 6;
  int gate = fragid >> 3, kt = (fragid >> 1) & 3, nt = fragid & 1;
  const float* __restrict__ w1 = gate ? g1w1 : g0w1;
#pragma unroll
  for (int j = 0; j < 8; ++j) {
    int k = kt * 32 + ((lane >> 4) << 3) + j;
    int o = nt * 16 + (lane & 15);
    wsf[fragid * 512 + lane * 8 + j] = bf16_rne(w1[k * 32 + o]);
  }
}

// One gate level: z = W1^T x (bf16-hi), W frags JIT-read from LDS in pairs;
// relu+layer2 per lane, 2-shuffle reduce, sigmoid, blend cur in place.
static __device__ __forceinline__ void gate_apply(
    const float (&fine)[16], float (&cur)[16], const uint4* wfl, int lane,
    f32x4 b1a, f32x4 b1b, f32x4 w2a, f32x4 w2b, float b2s) {
  v8s xf0, xf1, xc0, xc1;
#pragma unroll
  for (int e = 0; e < 8; ++e) {
    xf0[e] = (short)bf16_rne(fine[e]);
    xf1[e] = (short)bf16_rne(fine[8 + e]);
    xc0[e] = (short)bf16_rne(cur[e]);
    xc1[e] = (short)bf16_rne(cur[8 + e]);
  }
  f32x4 acc0 = b1a, acc1 = b1b;
  {
    uint4 wa = wfl[0 * 64 + lane], wb = wfl[1 * 64 + lane];
    acc0 = __builtin_amdgcn_mfma_f32_16x16x32_bf16(*(const v8s*)&wa, xf0, acc0, 0, 0, 0);
    acc1 = __builtin_amdgcn_mfma_f32_16x16x32_bf16(*(const v8s*)&wb, xf0, acc1, 0, 0, 0);
  }
  {
    uint4 wa = wfl[2 * 64 + lane], wb = wfl[3 * 64 + lane];
    acc0 = __builtin_amdgcn_mfma_f32_16x16x32_bf16(*(const v8s*)&wa, xf1, acc0, 0, 0, 0);
    acc1 = __builtin_amdgcn_mfma_f32_16x16x32_bf16(*(const v8s*)&wb, xf1, acc1, 0, 0, 0);
  }
  {
    uint4 wa = wfl[4 * 64 + lane], wb = wfl[5 * 64 + lane];
    acc0 = __builtin_amdgcn_mfma_f32_16x16x32_bf16(*(const v8s*)&wa, xc0, acc0, 0, 0, 0);
    acc1 = __builtin_amdgcn_mfma_f32_16x16x32_bf16(*(const v8s*)&wb, xc0, acc1, 0, 0, 0);
  }
  {
    uint4 wa = wfl[6 * 64 + lane], wb = wfl[7 * 64 + lane];
    acc0 = __builtin_amdgcn_mfma_f32_16x16x32_bf16(*(const v8s*)&wa, xc1, acc0, 0, 0, 0);
    acc1 = __builtin_amdgcn_mfma_f32_16x16x32_bf16(*(const v8s*)&wb, xc1, acc1, 0, 0, 0);
  }
  float zp = 0.f;
#pragma unroll
  for (int j = 0; j < 4; ++j)
    zp += fmaxf(acc0[j], 0.f) * w2a[j] + fmaxf(acc1[j], 0.f) * w2b[j];
  zp += __shfl_xor(zp, 16);
  zp += __shfl_xor(zp, 32);
  float g = 1.f / (1.f + __expf(-(zp + b2s)));
#pragma unroll
  for (int e = 0; e < 16; ++e) cur[e] = fmaf(g, fine[e] - cur[e], cur[e]);
}

__global__ __launch_bounds__(256, 2) void cascade_pipe(
    const int* __restrict__ ids0, const int* __restrict__ ids1,
    const int* __restrict__ ids2,
    const float* __restrict__ emb0, const float* __restrict__ emb1,
    const float* __restrict__ emb2,
    const uint4* __restrict__ wfrag,
    const float* __restrict__ b1_0, const float* __restrict__ w2_0,
    const float* __restrict__ b2_0,
    const float* __restrict__ b1_1, const float* __restrict__ w2_1,
    const float* __restrict__ b2_1,
    float* __restrict__ out, int n) {
  __shared__ uint4 WF[1024];            // 16 KB: frag f at WF[f*64 + lane]
  __shared__ float4 EB[WPB][3][256];    // per wave: emb2 | emb1 | emb0, 4 KB ea
  const int tid = threadIdx.x, lane = tid & 63, wave = tid >> 6;
  const int q = lane >> 4, t16 = lane & 15;
  const int ntiles = n >> 4;
  const int nw = NBLK * WPB;
  int tile = blockIdx.x * WPB + wave;
  if (tile >= ntiles) return;
  float4* myF = &EB[wave][0][0];

  // stage W fragments into LDS (256 thr x 4 x 16 B = 16 KB, linear)
#pragma unroll
  for (int k = 0; k < 4; ++k)
    __builtin_amdgcn_global_load_lds(
        (glb_u32_t*)((const char*)wfrag + (k * 256 + tid) * 16),
        (lds_u32_t*)(uint32_t*)&WF[k * 256 + tid], 16, 0, 0);

  // layer-2 params (per-lane, q-dependent)
  const f32x4 b1a0 = *(const f32x4*)&b1_0[q * 4], b1b0 = *(const f32x4*)&b1_0[16 + q * 4];
  const f32x4 w2a0 = *(const f32x4*)&w2_0[q * 4], w2b0 = *(const f32x4*)&w2_0[16 + q * 4];
  const f32x4 b1a1 = *(const f32x4*)&b1_1[q * 4], b1b1 = *(const f32x4*)&b1_1[16 + q * 4];
  const f32x4 w2a1 = *(const f32x4*)&w2_1[q * 4], w2b1 = *(const f32x4*)&w2_1[16 + q * 4];
  const float b2s0 = b2_0[0], b2s1 = b2_1[0];

  int jA0[4], jA1[4], jA2[4];   // gather ids for the NEXT tile to issue

  // 12 id loads for a tile (per-lane rows s*4+q of the tile)
  auto loadids = [&](int t, int (&i0)[4], int (&i1)[4], int (&i2)[4]) {
    int tb = (t << 4) + q;
#pragma unroll
    for (int s = 0; s < 4; ++s) {
      i0[s] = ids0[tb + s * 4];
      i1[s] = ids1[tb + s * 4];
      i2[s] = ids2[tb + s * 4];
    }
  };
  // 12 direct-to-LDS gathers, XOR-swizzled via pre-swizzled global source
  auto issue12 = [&](const int (&i0)[4], const int (&i1)[4], const int (&i2)[4]) {
#pragma unroll
    for (int s = 0; s < 4; ++s) {
      int swb = ((t16 ^ (s * 4 + q)) << 4);
      __builtin_amdgcn_global_load_lds(
          (glb_u32_t*)((const char*)emb2 + (((long)i2[s]) << 8) + swb),
          (lds_u32_t*)(uint32_t*)(myF + 0 * 256 + s * 64), 16, 0, 0);
      __builtin_amdgcn_global_load_lds(
          (glb_u32_t*)((const char*)emb1 + (((long)i1[s]) << 8) + swb),
          (lds_u32_t*)(uint32_t*)(myF + 1 * 256 + s * 64), 16, 0, 0);
      __builtin_amdgcn_global_load_lds(
          (glb_u32_t*)((const char*)emb0 + (((long)i0[s]) << 8) + swb),
          (lds_u32_t*)(uint32_t*)(myF + 2 * 256 + s * 64), 16, 0, 0);
    }
  };

  // ---- prologue: WF staged; gathers(tile0) in flight; jA = ids(tile0+nw)
  {
    int a0[4], a1[4], a2[4];
    loadids(tile, a0, a1, a2);
    __syncthreads();            // WF visible (drains all counters)
    issue12(a0, a1, a2);        // 12 gathers for tile0
    { int t2 = tile + nw; if (t2 >= ntiles) t2 = 0; loadids(t2, jA0, jA1, jA2); }
    asm volatile("s_waitcnt vmcnt(12)" ::: "memory");  // gathers(t0) done; ids fly
    __builtin_amdgcn_sched_barrier(0);
  }

  for (; tile < ntiles; tile += nw) {
    // steady state queue: gathers(12) | ids(12) | stores(4) -> vmcnt(16)
    asm volatile("s_waitcnt vmcnt(16)" ::: "memory");
    __builtin_amdgcn_sched_barrier(0);

    // pull this tile's fragments to registers (swizzled chunks of row t16)
    float curv[16], f1v[16], f0v[16];
#pragma unroll
    for (int e = 0; e < 4; ++e) {
      int ci = (2 * q + (e & 1) + 8 * (e >> 1)) ^ t16;
      *(float4*)&curv[e * 4] = myF[0 * 256 + t16 * 16 + ci];
      *(float4*)&f1v[e * 4]  = myF[1 * 256 + t16 * 16 + ci];
      *(float4*)&f0v[e * 4]  = myF[2 * 256 + t16 * 16 + ci];
    }
    asm volatile("s_waitcnt lgkmcnt(0)" ::: "memory");  // reads done -> LDS free
    __builtin_amdgcn_sched_barrier(0);

    // issue gathers for tile+nw (prefetch), then ids for tile+2nw
    issue12(jA0, jA1, jA2);
    { int t2 = tile + 2 * nw; if (t2 >= ntiles) t2 = 0; loadids(t2, jA0, jA1, jA2); }
    __builtin_amdgcn_sched_barrier(0);

    // gate level 1 (fine = emb1), then level 0 (fine = emb0); W from LDS
    gate_apply(f1v, curv, &WF[512], lane, b1a1, b1b1, w2a1, w2b1, b2s1);
    gate_apply(f0v, curv, &WF[0],   lane, b1a0, b1b0, w2a0, w2b0, b2s0);

    // store token (tile*16 + t16): 4 x 16 B (plain stores; L2 merges lines)
    long tok = ((long)tile << 4) + t16;
    if (tok < n) {
      float4* op = (float4*)out + (tok << 4);
      op[2 * q + 0]     = float4{curv[0], curv[1], curv[2], curv[3]};
      op[2 * q + 1]     = float4{curv[4], curv[5], curv[6], curv[7]};
      op[8 + 2 * q + 0] = float4{curv[8], curv[9], curv[10], curv[11]};
      op[8 + 2 * q + 1] = float4{curv[12], curv[13], curv[14], curv[15]};
    }
  }
}

extern "C" void kernel_launch(void* const* d_in, const int* in_sizes, int n_in,
                              void* d_out, int out_size, void* d_ws,
                              size_t ws_size, hipStream_t stream) {
  const int* ids0 = (const int*)d_in[0];
  const int* ids1 = (const int*)d_in[1];
  const int* ids2 = (const int*)d_in[2];
  const float* emb0 = (const float*)d_in[3];
  const float* emb1 = (const float*)d_in[4];
  const float* emb2 = (const float*)d_in[5];
  const float* g0w1 = (const float*)d_in[6];
  const float* g0b1 = (const float*)d_in[7];
  const float* g0w2 = (const float*)d_in[8];
  const float* g0b2 = (const float*)d_in[9];
  const float* g1w1 = (const float*)d_in[10];
  const float* g1b1 = (const float*)d_in[11];
  const float* g1w2 = (const float*)d_in[12];
  const float* g1b2 = (const float*)d_in[13];
  float* out = (float*)d_out;

  int n = in_sizes[0];  // B*H tokens

  hipLaunchKernelGGL(prep_frags, dim3(4), dim3(256), 0, stream,
                     g0w1, g1w1, (unsigned short*)d_ws);

  hipLaunchKernelGGL(cascade_pipe, dim3(NBLK), dim3(256), 0, stream,
                     ids0, ids1, ids2, emb0, emb1, emb2,
                     (const uint4*)d_ws,
                     g0b1, g0w2, g0b2,
                     g1b1, g1w2, g1b2,
                     out, n);
}

// Round 10
// 123.201 us; speedup vs baseline: 1.6781x; 1.0748x over previous
//
#include <hip/hip_runtime.h>

// CascadeHierarchicalEmbedding, R10 = R9 + NT cache policy on emb0 gathers.
// R9 (132.4us, best): all tables via swizzled global_load_lds into per-wave
// 4 KB LDS buffers; W1 frags in shared LDS; counted-vmcnt prefetch pipeline;
// plain merged stores. R10's single change: emb0's gathers carry aux=2 (NT):
// emb0 streams 210 MB/pass with ~no reuse (table 256 MB > L3) and evicts
// emb1 (L3-resident) + emb2 (L2-resident); NT makes emb0 evict-first so the
// reusable tables keep their residency -> less refetch, lower gather latency.

#define WPB 4       // waves per block (256 threads)
#define NBLK 512    // 512 blocks x 4 waves = 2048 waves = 2 blocks/CU

#define AUX_NT 2    // gfx940+ CPol: sc0=1, nt=2, sc1=16

typedef float f32x4 __attribute__((ext_vector_type(4)));
typedef short v8s __attribute__((ext_vector_type(8)));
typedef __attribute__((address_space(3))) uint32_t lds_u32_t;
typedef __attribute__((address_space(1))) const uint32_t glb_u32_t;

static __device__ __forceinline__ unsigned short bf16_rne(float f) {
  union { float f; unsigned int u; } a; a.f = f;
  return (unsigned short)((a.u + 0x7FFFu + ((a.u >> 16) & 1u)) >> 16);
}

// Pack W1 (f32 [128][32]) into bf16 A-fragments (W1^T). gate0: frags 0..7,
// gate1: frags 8..15. fragid = gate*8 + kt*2 + nt; elem (lane,j):
// k = kt*32 + (lane>>4)*8 + j, o = nt*16 + (lane&15) -> w1[k][o].
__global__ __launch_bounds__(256) void prep_frags(
    const float* __restrict__ g0w1, const float* __restrict__ g1w1,
    unsigned short* __restrict__ wsf) {
  int t = blockIdx.x * 256 + threadIdx.x;
  if (t >= 1024) return;
  int lane = t & 63, fragid = t >> 6;
  int gate = fragid >> 3, kt = (fragid >> 1) & 3, nt = fragid & 1;
  const float* __restrict__ w1 = gate ? g1w1 : g0w1;
#pragma unroll
  for (int j = 0; j < 8; ++j) {
    int k = kt * 32 + ((lane >> 4) << 3) + j;
    int o = nt * 16 + (lane & 15);
    wsf[fragid * 512 + lane * 8 + j] = bf16_rne(w1[k * 32 + o]);
  }
}

// One gate level: z = W1^T x (bf16-hi), W frags JIT-read from LDS in pairs;
// relu+layer2 per lane, 2-shuffle reduce, sigmoid, blend cur in place.
static __device__ __forceinline__ void gate_apply(
    const float (&fine)[16], float (&cur)[16], const uint4* wfl, int lane,
    f32x4 b1a, f32x4 b1b, f32x4 w2a, f32x4 w2b, float b2s) {
  v8s xf0, xf1, xc0, xc1;
#pragma unroll
  for (int e = 0; e < 8; ++e) {
    xf0[e] = (short)bf16_rne(fine[e]);
    xf1[e] = (short)bf16_rne(fine[8 + e]);
    xc0[e] = (short)bf16_rne(cur[e]);
    xc1[e] = (short)bf16_rne(cur[8 + e]);
  }
  f32x4 acc0 = b1a, acc1 = b1b;
  {
    uint4 wa = wfl[0 * 64 + lane], wb = wfl[1 * 64 + lane];
    acc0 = __builtin_amdgcn_mfma_f32_16x16x32_bf16(*(const v8s*)&wa, xf0, acc0, 0, 0, 0);
    acc1 = __builtin_amdgcn_mfma_f32_16x16x32_bf16(*(const v8s*)&wb, xf0, acc1, 0, 0, 0);
  }
  {
    uint4 wa = wfl[2 * 64 + lane], wb = wfl[3 * 64 + lane];
    acc0 = __builtin_amdgcn_mfma_f32_16x16x32_bf16(*(const v8s*)&wa, xf1, acc0, 0, 0, 0);
    acc1 = __builtin_amdgcn_mfma_f32_16x16x32_bf16(*(const v8s*)&wb, xf1, acc1, 0, 0, 0);
  }
  {
    uint4 wa = wfl[4 * 64 + lane], wb = wfl[5 * 64 + lane];
    acc0 = __builtin_amdgcn_mfma_f32_16x16x32_bf16(*(const v8s*)&wa, xc0, acc0, 0, 0, 0);
    acc1 = __builtin_amdgcn_mfma_f32_16x16x32_bf16(*(const v8s*)&wb, xc0, acc1, 0, 0, 0);
  }
  {
    uint4 wa = wfl[6 * 64 + lane], wb = wfl[7 * 64 + lane];
    acc0 = __builtin_amdgcn_mfma_f32_16x16x32_bf16(*(const v8s*)&wa, xc1, acc0, 0, 0, 0);
    acc1 = __builtin_amdgcn_mfma_f32_16x16x32_bf16(*(const v8s*)&wb, xc1, acc1, 0, 0, 0);
  }
  float zp = 0.f;
#pragma unroll
  for (int j = 0; j < 4; ++j)
    zp += fmaxf(acc0[j], 0.f) * w2a[j] + fmaxf(acc1[j], 0.f) * w2b[j];
  zp += __shfl_xor(zp, 16);
  zp += __shfl_xor(zp, 32);
  float g = 1.f / (1.f + __expf(-(zp + b2s)));
#pragma unroll
  for (int e = 0; e < 16; ++e) cur[e] = fmaf(g, fine[e] - cur[e], cur[e]);
}

__global__ __launch_bounds__(256, 2) void cascade_pipe(
    const int* __restrict__ ids0, const int* __restrict__ ids1,
    const int* __restrict__ ids2,
    const float* __restrict__ emb0, const float* __restrict__ emb1,
    const float* __restrict__ emb2,
    const uint4* __restrict__ wfrag,
    const float* __restrict__ b1_0, const float* __restrict__ w2_0,
    const float* __restrict__ b2_0,
    const float* __restrict__ b1_1, const float* __restrict__ w2_1,
    const float* __restrict__ b2_1,
    float* __restrict__ out, int n) {
  __shared__ uint4 WF[1024];            // 16 KB: frag f at WF[f*64 + lane]
  __shared__ float4 EB[WPB][3][256];    // per wave: emb2 | emb1 | emb0, 4 KB ea
  const int tid = threadIdx.x, lane = tid & 63, wave = tid >> 6;
  const int q = lane >> 4, t16 = lane & 15;
  const int ntiles = n >> 4;
  const int nw = NBLK * WPB;
  int tile = blockIdx.x * WPB + wave;
  if (tile >= ntiles) return;
  float4* myF = &EB[wave][0][0];

  // stage W fragments into LDS (256 thr x 4 x 16 B = 16 KB, linear)
#pragma unroll
  for (int k = 0; k < 4; ++k)
    __builtin_amdgcn_global_load_lds(
        (glb_u32_t*)((const char*)wfrag + (k * 256 + tid) * 16),
        (lds_u32_t*)(uint32_t*)&WF[k * 256 + tid], 16, 0, 0);

  // layer-2 params (per-lane, q-dependent)
  const f32x4 b1a0 = *(const f32x4*)&b1_0[q * 4], b1b0 = *(const f32x4*)&b1_0[16 + q * 4];
  const f32x4 w2a0 = *(const f32x4*)&w2_0[q * 4], w2b0 = *(const f32x4*)&w2_0[16 + q * 4];
  const f32x4 b1a1 = *(const f32x4*)&b1_1[q * 4], b1b1 = *(const f32x4*)&b1_1[16 + q * 4];
  const f32x4 w2a1 = *(const f32x4*)&w2_1[q * 4], w2b1 = *(const f32x4*)&w2_1[16 + q * 4];
  const float b2s0 = b2_0[0], b2s1 = b2_1[0];

  int jA0[4], jA1[4], jA2[4];   // gather ids for the NEXT tile to issue

  // 12 id loads for a tile (per-lane rows s*4+q of the tile)
  auto loadids = [&](int t, int (&i0)[4], int (&i1)[4], int (&i2)[4]) {
    int tb = (t << 4) + q;
#pragma unroll
    for (int s = 0; s < 4; ++s) {
      i0[s] = ids0[tb + s * 4];
      i1[s] = ids1[tb + s * 4];
      i2[s] = ids2[tb + s * 4];
    }
  };
  // 12 direct-to-LDS gathers, XOR-swizzled via pre-swizzled global source.
  // emb0 (256 MB table, streaming, no reuse) carries NT so it doesn't evict
  // emb1/emb2 from L2/L3.
  auto issue12 = [&](const int (&i0)[4], const int (&i1)[4], const int (&i2)[4]) {
#pragma unroll
    for (int s = 0; s < 4; ++s) {
      int swb = ((t16 ^ (s * 4 + q)) << 4);
      __builtin_amdgcn_global_load_lds(
          (glb_u32_t*)((const char*)emb2 + (((long)i2[s]) << 8) + swb),
          (lds_u32_t*)(uint32_t*)(myF + 0 * 256 + s * 64), 16, 0, 0);
      __builtin_amdgcn_global_load_lds(
          (glb_u32_t*)((const char*)emb1 + (((long)i1[s]) << 8) + swb),
          (lds_u32_t*)(uint32_t*)(myF + 1 * 256 + s * 64), 16, 0, 0);
      __builtin_amdgcn_global_load_lds(
          (glb_u32_t*)((const char*)emb0 + (((long)i0[s]) << 8) + swb),
          (lds_u32_t*)(uint32_t*)(myF + 2 * 256 + s * 64), 16, 0, AUX_NT);
    }
  };

  // ---- prologue: WF staged; gathers(tile0) in flight; jA = ids(tile0+nw)
  {
    int a0[4], a1[4], a2[4];
    loadids(tile, a0, a1, a2);
    __syncthreads();            // WF visible (drains all counters)
    issue12(a0, a1, a2);        // 12 gathers for tile0
    { int t2 = tile + nw; if (t2 >= ntiles) t2 = 0; loadids(t2, jA0, jA1, jA2); }
    asm volatile("s_waitcnt vmcnt(12)" ::: "memory");  // gathers(t0) done; ids fly
    __builtin_amdgcn_sched_barrier(0);
  }

  for (; tile < ntiles; tile += nw) {
    // steady state queue: gathers(12) | ids(12) | stores(4) -> vmcnt(16)
    asm volatile("s_waitcnt vmcnt(16)" ::: "memory");
    __builtin_amdgcn_sched_barrier(0);

    // pull this tile's fragments to registers (swizzled chunks of row t16)
    float curv[16], f1v[16], f0v[16];
#pragma unroll
    for (int e = 0; e < 4; ++e) {
      int ci = (2 * q + (e & 1) + 8 * (e >> 1)) ^ t16;
      *(float4*)&curv[e * 4] = myF[0 * 256 + t16 * 16 + ci];
      *(float4*)&f1v[e * 4]  = myF[1 * 256 + t16 * 16 + ci];
      *(float4*)&f0v[e * 4]  = myF[2 * 256 + t16 * 16 + ci];
    }
    asm volatile("s_waitcnt lgkmcnt(0)" ::: "memory");  // reads done -> LDS free
    __builtin_amdgcn_sched_barrier(0);

    // issue gathers for tile+nw (prefetch), then ids for tile+2nw
    issue12(jA0, jA1, jA2);
    { int t2 = tile + 2 * nw; if (t2 >= ntiles) t2 = 0; loadids(t2, jA0, jA1, jA2); }
    __builtin_amdgcn_sched_barrier(0);

    // gate level 1 (fine = emb1), then level 0 (fine = emb0); W from LDS
    gate_apply(f1v, curv, &WF[512], lane, b1a1, b1b1, w2a1, w2b1, b2s1);
    gate_apply(f0v, curv, &WF[0],   lane, b1a0, b1b0, w2a0, w2b0, b2s0);

    // store token (tile*16 + t16): 4 x 16 B (plain stores; L2 merges lines)
    long tok = ((long)tile << 4) + t16;
    if (tok < n) {
      float4* op = (float4*)out + (tok << 4);
      op[2 * q + 0]     = float4{curv[0], curv[1], curv[2], curv[3]};
      op[2 * q + 1]     = float4{curv[4], curv[5], curv[6], curv[7]};
      op[8 + 2 * q + 0] = float4{curv[8], curv[9], curv[10], curv[11]};
      op[8 + 2 * q + 1] = float4{curv[12], curv[13], curv[14], curv[15]};
    }
  }
}

extern "C" void kernel_launch(void* const* d_in, const int* in_sizes, int n_in,
                              void* d_out, int out_size, void* d_ws,
                              size_t ws_size, hipStream_t stream) {
  const int* ids0 = (const int*)d_in[0];
  const int* ids1 = (const int*)d_in[1];
  const int* ids2 = (const int*)d_in[2];
  const float* emb0 = (const float*)d_in[3];
  const float* emb1 = (const float*)d_in[4];
  const float* emb2 = (const float*)d_in[5];
  const float* g0w1 = (const float*)d_in[6];
  const float* g0b1 = (const float*)d_in[7];
  const float* g0w2 = (const float*)d_in[8];
  const float* g0b2 = (const float*)d_in[9];
  const float* g1w1 = (const float*)d_in[10];
  const float* g1b1 = (const float*)d_in[11];
  const float* g1w2 = (const float*)d_in[12];
  const float* g1b2 = (const float*)d_in[13];
  float* out = (float*)d_out;

  int n = in_sizes[0];  // B*H tokens

  hipLaunchKernelGGL(prep_frags, dim3(4), dim3(256), 0, stream,
                     g0w1, g1w1, (unsigned short*)d_ws);

  hipLaunchKernelGGL(cascade_pipe, dim3(NBLK), dim3(256), 0, stream,
                     ids0, ids1, ids2, emb0, emb1, emb2,
                     (const uint4*)d_ws,
                     g0b1, g0w2, g0b2,
                     g1b1, g1w2, g1b2,
                     out, n);
}